// Round 11
// baseline (428.572 us; speedup 1.0000x reference)
//
#include <hip/hip_runtime.h>
#include <hip/hip_bf16.h>

// Problem constants
#define B_     8
#define N_     1024
#define DIM_   512
#define H_     8
#define HD_    64
#define INNER_ 512
#define QKVC   2048   // 4*INNER
#define M_     8192   // B*N

typedef __attribute__((ext_vector_type(8))) short short8;
typedef __attribute__((ext_vector_type(4))) float f32x4;
#define MFMA_BF16 __builtin_amdgcn_mfma_f32_16x16x32_bf16

__device__ __forceinline__ unsigned short f2b(float x) {
    __hip_bfloat16 h = __float2bfloat16(x);
    unsigned short u; __builtin_memcpy(&u, &h, 2); return u;
}
__device__ __forceinline__ void split8(const float* v, short8& h, short8& l) {
#pragma unroll
    for (int i = 0; i < 8; i++) {
        unsigned int hb = f2b(v[i]);
        float fh = __uint_as_float(hb << 16);
        h[i] = (short)hb; l[i] = (short)f2b(v[i] - fh);
    }
}
// hi/lo split of two floats -> packed u32s (ushort order: a in low, b in high)
__device__ __forceinline__ void split2x2(float a, float b, unsigned int& h, unsigned int& l) {
    unsigned int ha = f2b(a), hb = f2b(b);
    float fa = __uint_as_float(ha << 16), fb = __uint_as_float(hb << 16);
    h = ha | (hb << 16);
    l = (unsigned int)f2b(a - fa) | ((unsigned int)f2b(b - fb) << 16);
}

// async global->LDS, 16B per lane, LDS dest = wave-uniform base + lane*16
__device__ __forceinline__ void gll16(const unsigned short* g, unsigned short* l) {
    __builtin_amdgcn_global_load_lds(
        (const __attribute__((address_space(1))) void*)g,
        (__attribute__((address_space(3))) void*)l, 16, 0, 0);
}

// ---------------------------------------------------------------------------
// Layout notes
//  GEMM A/B image: tile (rt,kt) = 8192 ushorts at ((rt*16+kt)<<13); within,
//    row r = 64 ushorts; hi of kk at (((kk>>3)^(r&7))<<3)+(kk&7), lo at
//    ((((kk>>3)+4)^(r&7))<<3)+(kk&7).
//  K planar image: per token row, [hi-plane 64 ushorts][lo-plane 64 ushorts].
//  V image: per (b,h), 16 blocks of 64 tokens; block = EXACT sV LDS image:
//    idx = d*64 + (((j>>3) ^ ((d^(d>>2))&7))<<3) + (j&7).
// ---------------------------------------------------------------------------

// merged pair via blockIdx.y select
__global__ __launch_bounds__(256)
void pack_a_tiled(const float* __restrict__ in0, const float* __restrict__ in1,
                  unsigned short* __restrict__ out0, unsigned short* __restrict__ out1)
{
    const float* in = blockIdx.y ? in1 : in0;
    unsigned short* out = blockIdx.y ? out1 : out0;
    size_t i = ((size_t)blockIdx.x * 256 + threadIdx.x) * 4;   // element idx, K=512 cols
    float4 v = *(const float4*)(in + i);
    const size_t R = i >> 9;          // row
    const int k  = (int)(i & 511);    // col (multiple of 4)
    const int kt = k >> 5, kk = k & 31;
    const int r  = (int)(R & 127);
    const size_t rt = R >> 7;
    unsigned short* tile = out + (((rt << 4) + kt) << 13) + r * 64;
    unsigned int h01, l01, h23, l23;
    split2x2(v.x, v.y, h01, l01);
    split2x2(v.z, v.w, h23, l23);
    uint2 hv; hv.x = h01; hv.y = h23;
    uint2 lv; lv.x = l01; lv.y = l23;
    const int s7 = r & 7;
    *(uint2*)&tile[(((kk >> 3)     ^ s7) << 3) + (kk & 7)] = hv;
    *(uint2*)&tile[((((kk >> 3)+4) ^ s7) << 3) + (kk & 7)] = lv;
}

// W[k][n] (f32, K=512 rows, N cols) -> B^T tiled image; merged pair via z
__global__ __launch_bounds__(256)
void pack_w_tiled(const float* __restrict__ W0, const float* __restrict__ W1,
                  unsigned short* __restrict__ out0, unsigned short* __restrict__ out1,
                  int N)
{
    const float* W = blockIdx.z ? W1 : W0;
    unsigned short* out = blockIdx.z ? out1 : out0;
    const int n  = blockIdx.x * 256 + threadIdx.x;
    const int k0 = blockIdx.y * 4;
    float f0 = W[(size_t)(k0 + 0) * N + n];
    float f1 = W[(size_t)(k0 + 1) * N + n];
    float f2 = W[(size_t)(k0 + 2) * N + n];
    float f3 = W[(size_t)(k0 + 3) * N + n];
    const int r  = n & 127;
    const size_t rt = n >> 7;
    const int kt = k0 >> 5, kk = k0 & 31;
    unsigned short* tile = out + (((rt << 4) + kt) << 13) + r * 64;
    unsigned int h01, l01, h23, l23;
    split2x2(f0, f1, h01, l01);
    split2x2(f2, f3, h23, l23);
    uint2 hv; hv.x = h01; hv.y = h23;
    uint2 lv; lv.x = l01; lv.y = l23;
    const int s7 = r & 7;
    *(uint2*)&tile[(((kk >> 3)     ^ s7) << 3) + (kk & 7)] = hv;
    *(uint2*)&tile[((((kk >> 3)+4) ^ s7) << 3) + (kk & 7)] = lv;
}

// ---------------------------------------------------------------------------
// MFMA split-GEMM, global_load_lds staging from pre-swizzled tiled inputs.
// XCD-aware block remap (T1): nwg%8==0 -> bijective; each XCD gets a
// contiguous (m,n) chunk so A-panels stay L2-resident.
// NPROB=2: z selects problem. PACKK: k-slice cols written as planar K-image.
// ---------------------------------------------------------------------------
template<bool BIAS, bool PACKK, int NPROB>
__global__ __launch_bounds__(256)
void gemm_gll(const unsigned short* __restrict__ At0, const unsigned short* __restrict__ At1,
              const unsigned short* __restrict__ Bt0, const unsigned short* __restrict__ Bt1,
              const float* __restrict__ bias0, const float* __restrict__ bias1,
              float* __restrict__ Cp0, float* __restrict__ Cp1,
              int M, int N)
{
    __shared__ __align__(16) unsigned short sA[128 * 64];
    __shared__ __align__(16) unsigned short sB[128 * 64];

    // XCD-aware remap
    const int nwx = gridDim.x, nwy = gridDim.y;
    int lin = blockIdx.x + nwx * (blockIdx.y + nwy * blockIdx.z);
    const int cpx = (nwx * nwy * gridDim.z) >> 3;
    lin = (lin & 7) * cpx + (lin >> 3);
    const int bx = lin % nwx;
    const int tmp2 = lin / nwx;
    const int by = tmp2 % nwy;
    const int bz = tmp2 / nwy;

    const int z = (NPROB == 2) ? bz : 0;
    const unsigned short* At = z ? At1 : At0;
    const unsigned short* Bt = z ? Bt1 : Bt0;
    const float* bias        = z ? bias1 : bias0;
    float* Cp                = z ? Cp1 : Cp0;

    const int t    = threadIdx.x;
    const int lane = t & 63;
    const int w    = t >> 6;
    const int n16  = lane & 15, quad = lane >> 4;
    const int wm   = w >> 1, wn = w & 1;
    const int m0 = by * 128, n0 = bx * 128;

    f32x4 acc[4][4];
#pragma unroll
    for (int mt = 0; mt < 4; mt++)
#pragma unroll
        for (int nt = 0; nt < 4; nt++) acc[mt][nt] = (f32x4){0.f, 0.f, 0.f, 0.f};

    const unsigned short* Ag = At + ((size_t)by << 4) * 8192 + (w * 64 + lane) * 8;
    const unsigned short* Bg = Bt + ((size_t)bx << 4) * 8192 + (w * 64 + lane) * 8;
    unsigned short* sAw = &sA[w * 512];
    unsigned short* sBw = &sB[w * 512];

    for (int kt = 0; kt < 16; kt++) {
        __syncthreads();
        const size_t ko = (size_t)kt * 8192;
#pragma unroll
        for (int i = 0; i < 4; i++) {
            gll16(Ag + ko + i * 2048, sAw + i * 2048);
            gll16(Bg + ko + i * 2048, sBw + i * 2048);
        }
        __syncthreads();

        short8 Ah[4], Al[4];
#pragma unroll
        for (int mt = 0; mt < 4; mt++) {
            const int row = 64 * wm + 16 * mt + n16;
            const int base = row * 64;
            const int s7 = row & 7;
            Ah[mt] = *(const short8*)&sA[base + (((quad    ) ^ s7) << 3)];
            Al[mt] = *(const short8*)&sA[base + (((quad + 4) ^ s7) << 3)];
        }
#pragma unroll
        for (int nt = 0; nt < 4; nt++) {
            const int row = 64 * wn + 16 * nt + n16;
            const int base = row * 64;
            const int s7 = row & 7;
            short8 Bh = *(const short8*)&sB[base + (((quad    ) ^ s7) << 3)];
            short8 Bl = *(const short8*)&sB[base + (((quad + 4) ^ s7) << 3)];
#pragma unroll
            for (int mt = 0; mt < 4; mt++) {
                acc[mt][nt] = MFMA_BF16(Ah[mt], Bh, acc[mt][nt], 0, 0, 0);
                acc[mt][nt] = MFMA_BF16(Al[mt], Bh, acc[mt][nt], 0, 0, 0);
                acc[mt][nt] = MFMA_BF16(Ah[mt], Bl, acc[mt][nt], 0, 0, 0);
            }
        }
    }

    const bool packout = PACKK && ((n0 >> 9) == 1);   // qkv k-slice cols
    float bv[4];
#pragma unroll
    for (int nt = 0; nt < 4; nt++)
        bv[nt] = BIAS ? bias[n0 + 64 * wn + 16 * nt + n16] : 0.f;
#pragma unroll
    for (int mt = 0; mt < 4; mt++) {
        const int rbase = m0 + 64 * wm + 16 * mt + 4 * quad;
#pragma unroll
        for (int r = 0; r < 4; r++) {
#pragma unroll
            for (int nt = 0; nt < 4; nt++) {
                const int col = n0 + 64 * wn + 16 * nt + n16;
                const int row = rbase + r;
                const float v = acc[mt][nt][r] + bv[nt];
                if (packout) {
                    // planar K-image: hi at [1024+dg], lo at [1536+dg]
                    const int dg = col & 511;
                    unsigned int hb = f2b(v);
                    float fh = __uint_as_float(hb << 16);
                    unsigned short* kim = (unsigned short*)Cp + (size_t)row * (2 * N);
                    kim[1024 + dg] = (unsigned short)hb;
                    kim[1536 + dg] = f2b(v - fh);
                } else {
                    Cp[(size_t)row * N + col] = v;
                }
            }
        }
    }
}

// ---------------------------------------------------------------------------
// Depthwise conv (k=5, pad=2) + sigmoid gate. Writes MSg (f32) + planar
// K-image [bh][n][hi 64 | lo 64] for attention A.
// ---------------------------------------------------------------------------
__global__ __launch_bounds__(128)
void convgate_kernel(const float* __restrict__ qkv1, const float* __restrict__ qkv2,
                     const float* __restrict__ convw,
                     const float* __restrict__ convb,
                     float* __restrict__ MSg, unsigned short* __restrict__ Kimg)
{
    __shared__ float ms[INNER_];
    const int blk = blockIdx.x;
    const int n = blk & (N_ - 1);
    const int b = blk >> 10;
    const int t = threadIdx.x;

    const float4* q1 = (const float4*)(qkv1 + (size_t)blk * QKVC + 3 * INNER_);
    const float4* q2 = (const float4*)(qkv2 + (size_t)blk * QKVC + 3 * INNER_);
    float4 v1 = q1[t], v2 = q2[t];
    float4 s;
    s.x = v1.x + v2.x; s.y = v1.y + v2.y; s.z = v1.z + v2.z; s.w = v1.w + v2.w;
    *(float4*)&ms[t * 4] = s;
    __syncthreads();

    float w[5];
#pragma unroll
    for (int k = 0; k < 5; k++) w[k] = convw[n * 5 + k];
    const float cb = convb[n];

    float out[4];
#pragma unroll
    for (int ff = 0; ff < 4; ff++) {
        int f = t * 4 + ff;
        float A = cb;
#pragma unroll
        for (int k = 0; k < 5; k++) {
            int idx = f + k - 2;
            if (idx >= 0 && idx < INNER_) A += ms[idx] * w[k];
        }
        float sg = 1.f / (1.f + __expf(-A));
        out[ff] = ms[f] * sg;
    }
    *(float4*)&MSg[(size_t)blk * INNER_ + t * 4] = make_float4(out[0], out[1], out[2], out[3]);

    // planar K-image write: head h = t>>4, dims d0..d0+3, token row n
    const int h  = t >> 4;
    const int d0 = (4 * t) & 63;
    unsigned short hs[4], ls[4];
#pragma unroll
    for (int e = 0; e < 4; e++) {
        unsigned int hb = f2b(out[e]);
        float fh = __uint_as_float(hb << 16);
        hs[e] = (unsigned short)hb;
        ls[e] = f2b(out[e] - fh);
    }
    unsigned short* kim = Kimg + ((size_t)(b * 8 + h) * 1024 + n) * 128 + d0;
    uint2 hv; hv.x = (unsigned int)hs[0] | ((unsigned int)hs[1] << 16);
              hv.y = (unsigned int)hs[2] | ((unsigned int)hs[3] << 16);
    uint2 lv; lv.x = (unsigned int)ls[0] | ((unsigned int)ls[1] << 16);
              lv.y = (unsigned int)ls[2] | ((unsigned int)ls[3] << 16);
    *(uint2*)kim        = hv;
    *(uint2*)(kim + 64) = lv;
}

// ---------------------------------------------------------------------------
// MFMA flash attention: 512 threads, Q-tile 128, simple 2-barrier loop.
// K staged via gll from planar image. VIMG: V via one linear gll16/thread.
// IMGO: outputs as u V-images (8B register scatter). IMGA: outputs as GEMM
// A-image (2B register scatter). setprio(1) around MFMA clusters (T5).
// Softmax in log2 domain (Q pre-scaled by 0.125*log2e) with defer-max.
// ---------------------------------------------------------------------------
template<int NV, bool RESID, bool IMGO, bool IMGA, bool VIMG, int NPROB>
__global__ __launch_bounds__(512, 2)
void mattn_kernel(const float* __restrict__ Q0, const float* __restrict__ Q1,
                  const unsigned short* __restrict__ K0, const unsigned short* __restrict__ K1,
                  const float* __restrict__ VA0, const float* __restrict__ VA1,
                  const float* __restrict__ VB0, const float* __restrict__ VB1,
                  float* __restrict__ OA0, float* __restrict__ OA1,
                  float* __restrict__ OB0, float* __restrict__ OB1,
                  long long q_sb, long long q_sh, int q_sr,
                  long long k_sb, long long k_sh, int k_rs, int k_po,
                  long long v_sb, long long v_sh, int v_sr,
                  long long o_sb, long long o_sh, int o_sr)
{
    __shared__ __align__(16) unsigned short sK[64 * 128];   // hi|lo planes
    __shared__ __align__(16) unsigned short sV0[64 * 64];   // V^T plain bf16
    __shared__ __align__(16) unsigned short sV1[(NV == 2) ? 64 * 64 : 8];
    __shared__ __align__(16) unsigned short sP[128 * 64];   // P plain bf16

    const int t    = threadIdx.x;
    const int w    = t >> 6;        // wave 0..7
    const int lane = t & 63;
    const int n16  = lane & 15;
    const int quad = lane >> 4;

    // XCD-aware decode
    const int bid = blockIdx.x;
    const int c   = bid & 7;
    const int r1  = bid >> 3;
    const int qt  = r1 & 7;
    const int r2  = r1 >> 3;
    const int g   = r2 & 7;
    const int p   = (NPROB == 2) ? (r2 >> 3) : 0;
    const int bh  = 8 * g + c;
    const int b = bh >> 3, h = bh & 7;
    const int i0 = qt * 128;

    const float* Qb          = (NPROB == 2 && p) ? Q1 : Q0;
    const unsigned short* Kb = (NPROB == 2 && p) ? K1 : K0;
    const float* VAb         = (NPROB == 2 && p) ? VA1 : VA0;
    float* OAb               = (NPROB == 2 && p) ? OA1 : OA0;

    const float* Qg          = Qb + (size_t)b * q_sb + (size_t)h * q_sh;
    const unsigned short* Kg = Kb + (size_t)b * k_sb + (size_t)h * k_sh;

    const float* V0g = nullptr;
    const float* V1g = nullptr;
    const unsigned short* Vus = nullptr;
    if constexpr (VIMG) {
        Vus = (const unsigned short*)VAb + (size_t)b * v_sb + (size_t)h * v_sh;
    } else {
        V0g = VAb + (size_t)b * v_sb + (size_t)h * v_sh;
        if constexpr (NV == 2)
            V1g = VB0 + (size_t)b * v_sb + (size_t)h * v_sh;
    }

    float* O0g = nullptr; float* O1g = nullptr;
    unsigned short* img0 = nullptr; unsigned short* img1 = nullptr;
    if constexpr (IMGO) {
        img0 = (unsigned short*)OAb + (size_t)b * o_sb + (size_t)h * o_sh;
        if constexpr (NV == 2)
            img1 = (unsigned short*)OB0 + (size_t)b * o_sb + (size_t)h * o_sh;
    } else if constexpr (IMGA) {
        img0 = (unsigned short*)OAb;   // full M x 512 A-image base
    } else {
        O0g = OAb + (size_t)b * o_sb + (size_t)h * o_sh;
        if constexpr (NV == 2)
            O1g = OB0 + (size_t)b * o_sb + (size_t)h * o_sh;
    }

    // persistent Q fragments (hi/lo split), rows i0+16w+n16,
    // pre-scaled by 0.125 * log2(e) so exps are bare v_exp_f32.
    const float SC2 = 0.1803368801f;
    short8 Qh[2], Ql[2];
#pragma unroll
    for (int s = 0; s < 2; s++) {
        const float* qp = Qg + (size_t)(i0 + 16 * w + n16) * q_sr + 32 * s + 8 * quad;
        float qv[8];
        float4 q0 = *(const float4*)qp;
        float4 q1 = *(const float4*)(qp + 4);
        qv[0]=q0.x*SC2; qv[1]=q0.y*SC2; qv[2]=q0.z*SC2; qv[3]=q0.w*SC2;
        qv[4]=q1.x*SC2; qv[5]=q1.y*SC2; qv[6]=q1.z*SC2; qv[7]=q1.w*SC2;
        split8(qv, Qh[s], Ql[s]);
    }

    float m_ = -1e30f, l_ = 0.f;
    f32x4 O0a[4], O1a[(NV == 2) ? 4 : 1];
#pragma unroll
    for (int nt = 0; nt < 4; nt++) O0a[nt] = (f32x4){0.f,0.f,0.f,0.f};
    if constexpr (NV == 2) {
#pragma unroll
        for (int nt = 0; nt < 4; nt++) O1a[nt] = (f32x4){0.f,0.f,0.f,0.f};
    }

    const int prow = 16 * w + n16;          // 0..127
    const int vc = t & 15, vp = t >> 4;     // V f32 staging: d-chunk, j-pair

    // K staging: lane l of wave w fills sK rows jr=4w+(l>>4) (+32), chunk q=l&15.
    // Planar source: logical chunk lq = q ^ (jr&15) -> plane lq>>3, dchunk lq&7.
    const int jr_l = (w << 2) + (lane >> 4);
    const int lq   = (lane & 15) ^ (jr_l & 15);
    const unsigned short* kg_base = Kg + (size_t)jr_l * k_rs
                                  + (lq >> 3) * k_po + (lq & 7) * 8;
    unsigned short* sKw = &sK[w * 512];

    for (int j0 = 0; j0 < N_; j0 += 64) {
        __syncthreads();

        // ---- stage K: 2x gll16 from planar image
        {
            const unsigned short* kg = kg_base + (size_t)j0 * k_rs;
            gll16(kg, sKw);
            gll16(kg + (size_t)32 * k_rs, sKw + 4096);
        }
        // ---- stage V
        if constexpr (VIMG) {
            gll16(Vus + (size_t)(j0 >> 6) * 4096 + t * 8, &sV0[w * 512]);
        } else {
            const int j = 2 * vp;
            const float* a0 = V0g + (size_t)(j0 + j) * v_sr + 4 * vc;
            float4 va = *(const float4*)a0;
            float4 vb = *(const float4*)(a0 + v_sr);
#pragma unroll
            for (int e = 0; e < 4; e++) {
                float fa = (e==0)?va.x:(e==1)?va.y:(e==2)?va.z:va.w;
                float fb = (e==0)?vb.x:(e==1)?vb.y:(e==2)?vb.z:vb.w;
                unsigned int u = (unsigned int)f2b(fa) | ((unsigned int)f2b(fb) << 16);
                const int d = 4 * vc + e;
                const int phys = (vp >> 2) ^ ((d ^ (d >> 2)) & 7);
                *(unsigned int*)&sV0[d * 64 + (phys << 3) + (j & 7)] = u;
            }
            if constexpr (NV == 2) {
                const float* a1 = V1g + (size_t)(j0 + j) * v_sr + 4 * vc;
                float4 wa = *(const float4*)a1;
                float4 wb = *(const float4*)(a1 + v_sr);
#pragma unroll
                for (int e = 0; e < 4; e++) {
                    float fa = (e==0)?wa.x:(e==1)?wa.y:(e==2)?wa.z:wa.w;
                    float fb = (e==0)?wb.x:(e==1)?wb.y:(e==2)?wb.z:wb.w;
                    unsigned int u = (unsigned int)f2b(fa) | ((unsigned int)f2b(fb) << 16);
                    const int d = 4 * vc + e;
                    const int phys = (vp >> 2) ^ ((d ^ (d >> 2)) & 7);
                    *(unsigned int*)&sV1[d * 64 + (phys << 3) + (j & 7)] = u;
                }
            }
        }
        __syncthreads();   // drains gll vmcnt + V lgkm

        // ---- S^T = K.Q^T, split 3-MFMA, frags straight from planes
        f32x4 accS[4];
#pragma unroll
        for (int mt = 0; mt < 4; mt++) accS[mt] = (f32x4){0.f,0.f,0.f,0.f};
        __builtin_amdgcn_s_setprio(1);
#pragma unroll
        for (int s = 0; s < 2; s++) {
#pragma unroll
            for (int mt = 0; mt < 4; mt++) {
                const unsigned short* kb2 = &sK[(16 * mt + n16) * 128];
                short8 kh = *(const short8*)&kb2[(((4*s + quad)    ) ^ n16) << 3];
                short8 kl = *(const short8*)&kb2[(((4*s + quad) + 8) ^ n16) << 3];
                accS[mt] = MFMA_BF16(kl, Qh[s], accS[mt], 0, 0, 0);
                accS[mt] = MFMA_BF16(kh, Ql[s], accS[mt], 0, 0, 0);
                accS[mt] = MFMA_BF16(kh, Qh[s], accS[mt], 0, 0, 0);
            }
        }
        __builtin_amdgcn_s_setprio(0);

        // ---- online softmax (log2 domain), defer-max, wave-local P store
        float tmax = -1e30f;
#pragma unroll
        for (int mt = 0; mt < 4; mt++)
#pragma unroll
            for (int r = 0; r < 4; r++) tmax = fmaxf(tmax, accS[mt][r]);
        tmax = fmaxf(tmax, __shfl_xor(tmax, 16));
        tmax = fmaxf(tmax, __shfl_xor(tmax, 32));
        if (!__all(tmax <= m_ + 11.0f)) {
            const float mnew = fmaxf(m_, tmax);
            const float alpha = __builtin_amdgcn_exp2f(m_ - mnew);
            m_ = mnew;
            l_ *= alpha;
            float ar[4];
#pragma unroll
            for (int r = 0; r < 4; r++) ar[r] = __shfl(alpha, (quad << 2) + r);
#pragma unroll
            for (int nt = 0; nt < 4; nt++) {
#pragma unroll
                for (int r = 0; r < 4; r++) O0a[nt][r] *= ar[r];
                if constexpr (NV == 2)
#pragma unroll
                    for (int r = 0; r < 4; r++) O1a[nt][r] *= ar[r];
            }
        }
        float rsum = 0.f;
#pragma unroll
        for (int mt = 0; mt < 4; mt++) {
            float p0 = __builtin_amdgcn_exp2f(accS[mt][0] - m_);
            float p1 = __builtin_amdgcn_exp2f(accS[mt][1] - m_);
            float p2 = __builtin_amdgcn_exp2f(accS[mt][2] - m_);
            float p3 = __builtin_amdgcn_exp2f(accS[mt][3] - m_);
            rsum += (p0 + p1) + (p2 + p3);
            uint2 u;
            u.x = (unsigned int)f2b(p0) | ((unsigned int)f2b(p1) << 16);
            u.y = (unsigned int)f2b(p2) | ((unsigned int)f2b(p3) << 16);
            const int phys = (2 * mt + (quad >> 1)) ^ (n16 & 7);
            *(uint2*)&sP[prow * 64 + (phys << 3) + 4 * (quad & 1)] = u;
        }
        rsum += __shfl_xor(rsum, 16);
        rsum += __shfl_xor(rsum, 32);
        l_ += rsum;

        // ---- PV: plain bf16, 1 MFMA per fragment
        __builtin_amdgcn_s_setprio(1);
#pragma unroll
        for (int s = 0; s < 2; s++) {
            short8 Pf = *(const short8*)&sP[prow * 64 + (((4*s + quad) ^ (n16 & 7)) << 3)];
#pragma unroll
            for (int nt = 0; nt < 4; nt++) {
                const int d = 16 * nt + n16;
                const int phys = (4*s + quad) ^ ((d ^ (d >> 2)) & 7);
                short8 vf = *(const short8*)&sV0[d * 64 + (phys << 3)];
                O0a[nt] = MFMA_BF16(Pf, vf, O0a[nt], 0, 0, 0);
                if constexpr (NV == 2) {
                    short8 vf1 = *(const short8*)&sV1[d * 64 + (phys << 3)];
                    O1a[nt] = MFMA_BF16(Pf, vf1, O1a[nt], 0, 0, 0);
                }
            }
        }
        __builtin_amdgcn_s_setprio(0);
    }

    // ---- epilogue
    float linv[4];
#pragma unroll
    for (int r = 0; r < 4; r++) linv[r] = 1.0f / __shfl(l_, (quad << 2) + r);

    if constexpr (IMGO) {
        // Direct register-scatter u V-image write (8B stores).
        const int blk = 2 * qt + (w >> 2);
        const int jg  = (2 * w + (quad >> 1)) & 7;
        const int j7b = 4 * (quad & 1);
#pragma unroll
        for (int nt = 0; nt < 4; nt++) {
            const int d = 16 * nt + n16;
            const int swd = (d ^ (d >> 2)) & 7;
            const size_t off = (size_t)blk * 4096 + d * 64 + ((jg ^ swd) << 3) + j7b;
            unsigned short o0[4], o1[4];
#pragma unroll
            for (int r = 0; r < 4; r++) {
                const int row = i0 + 16 * w + 4 * quad + r;
                float v = O0a[nt][r] * linv[r];
                if constexpr (RESID) v += V0g[(size_t)row * v_sr + d];
                o0[r] = f2b(v);
                if constexpr (NV == 2) {
                    float v1 = O1a[nt][r] * linv[r];
                    if constexpr (RESID) v1 += V1g[(size_t)row * v_sr + d];
                    o1[r] = f2b(v1);
                }
            }
            uint2 u0;
            u0.x = (unsigned int)o0[0] | ((unsigned int)o0[1] << 16);
            u0.y = (unsigned int)o0[2] | ((unsigned int)o0[3] << 16);
            *(uint2*)&img0[off] = u0;
            if constexpr (NV == 2) {
                uint2 u1v;
                u1v.x = (unsigned int)o1[0] | ((unsigned int)o1[1] << 16);
                u1v.y = (unsigned int)o1[2] | ((unsigned int)o1[3] << 16);
                *(uint2*)&img1[off] = u1v;
            }
        }
    } else if constexpr (IMGA) {
        // Direct register-scatter GEMM A-image write (2B stores, R8: free).
        const size_t rt = (size_t)b * 8 + qt;
#pragma unroll
        for (int r = 0; r < 4; r++) {
            const int rr  = 16 * w + 4 * quad + r;
            const int s7v = rr & 7;
#pragma unroll
            for (int nt = 0; nt < 4; nt++) {
                const int k   = h * 64 + 16 * nt + n16;
                const int kt2 = k >> 5, kk = k & 31;
                unsigned short* tile = img0 + (((rt << 4) + kt2) << 13) + rr * 64;
                float v = O0a[nt][r] * linv[r];
                unsigned int hb = f2b(v);
                float fh = __uint_as_float(hb << 16);
                tile[(((kk >> 3)     ^ s7v) << 3) + (kk & 7)] = (unsigned short)hb;
                tile[((((kk >> 3)+4) ^ s7v) << 3) + (kk & 7)] = f2b(v - fh);
            }
        }
    } else {
#pragma unroll
        for (int r = 0; r < 4; r++) {
            const int row = i0 + 16 * w + 4 * quad + r;
#pragma unroll
            for (int nt = 0; nt < 4; nt++) {
                const int col = 16 * nt + n16;
                float v = O0a[nt][r] * linv[r];
                if constexpr (RESID) v += V0g[(size_t)row * v_sr + col];
                O0g[(size_t)row * o_sr + col] = v;
                if constexpr (NV == 2) {
                    float v1 = O1a[nt][r] * linv[r];
                    if constexpr (RESID) v1 += V1g[(size_t)row * v_sr + col];
                    O1g[(size_t)row * o_sr + col] = v1;
                }
            }
        }
    }
}

// ---------------------------------------------------------------------------
extern "C" void kernel_launch(void* const* d_in, const int* in_sizes, int n_in,
                              void* d_out, int out_size, void* d_ws, size_t ws_size,
                              hipStream_t stream)
{
    const float* x1    = (const float*)d_in[0];
    const float* x2    = (const float*)d_in[1];
    const float* Wqkv1 = (const float*)d_in[2];
    const float* Wqkv2 = (const float*)d_in[3];
    const float* Wout1 = (const float*)d_in[4];
    const float* bout1 = (const float*)d_in[5];
    const float* Wout2 = (const float*)d_in[6];
    const float* bout2 = (const float*)d_in[7];
    const float* convw = (const float*)d_in[8];
    const float* convb = (const float*)d_in[9];

    const size_t QKV_ELEMS = (size_t)M_ * QKVC;
    const size_t BND_ELEMS = (size_t)M_ * INNER_;
    if (ws_size < (2 * QKV_ELEMS + 5 * BND_ELEMS) * sizeof(float)) return;

    float* ws   = (float*)d_ws;
    float* qkv1 = ws;
    float* qkv2 = qkv1 + QKV_ELEMS;
    float* MSg  = qkv2 + QKV_ELEMS;
    float* u1   = MSg + BND_ELEMS;
    float* u2   = u1 + BND_ELEMS;
    float* t1m  = u2 + BND_ELEMS;
    float* t2m  = t1m + BND_ELEMS;

    // Aliased buffers (time-disjoint):
    unsigned short* x1t   = (unsigned short*)t1m;  // tiled A image, consumed step 1
    unsigned short* x2t   = (unsigned short*)t2m;  // tiled A image, consumed step 1
    unsigned short* KimgA = (unsigned short*)t1m;  // attn-A K-image, step 2 -> 3
    unsigned short* w1t   = (unsigned short*)u2;   // tiled B images [0,8MB), step 1
    unsigned short* w2t   = w1t + (size_t)QKVC * DIM_ * 2;
    unsigned short* wo1t  = w1t + (size_t)2 * QKVC * DIM_ * 2;  // u2 tail [8,10MB), free always
    unsigned short* wo2t  = wo1t + (size_t)DIM_ * DIM_ * 2;
    unsigned short* u1img = (unsigned short*)u1;   // u V-image, step 3 -> 4
    unsigned short* u2img = (unsigned short*)u2;
    unsigned short* t1img = (unsigned short*)t1m;  // t A-image, step 4 -> 5
    unsigned short* t2img = (unsigned short*)t2m;

    dim3 blk(256);

    // 0) pack activations + all weights into pre-swizzled tiled images
    pack_a_tiled<<<dim3(M_ * DIM_ / 1024, 2), blk, 0, stream>>>(x1, x2, x1t, x2t);
    pack_w_tiled<<<dim3(QKVC / 256, DIM_ / 4, 2), blk, 0, stream>>>(
        Wqkv1, Wqkv2, w1t, w2t, QKVC);
    pack_w_tiled<<<dim3(DIM_ / 256, DIM_ / 4, 2), blk, 0, stream>>>(
        Wout1, Wout2, wo1t, wo2t, DIM_);

    // 1) QKV projections, MERGED pair (z=2), XCD-swizzled;
    //    k-slice cols [512,1024) written as planar K-image
    gemm_gll<false, true, 2><<<dim3(QKVC / 128, M_ / 128, 2), blk, 0, stream>>>(
        x1t, x2t, w1t, w2t, nullptr, nullptr, qkv1, qkv2, M_, QKVC);

    // 2) conv + sigmoid gate -> MSg (f32) + planar K-image for attn A
    convgate_kernel<<<dim3(M_), dim3(128), 0, stream>>>(qkv1, qkv2, convw, convb,
                                                        MSg, KimgA);

    // Stride descriptors
    const long long msg_sb = (long long)N_ * INNER_, msg_sh = HD_;
    const int       msg_sr = INNER_;
    const long long qkv_sb = (long long)N_ * QKVC, qkv_sh = HD_;
    const int       qkv_sr = QKVC;
    // K-image strides (ushort units)
    const long long kA_sb = (long long)8 * N_ * 128, kA_sh = (long long)N_ * 128;
    const long long kB_sb = (long long)N_ * QKVC * 2;
    // u V-image strides (ushort units)
    const long long ui_sb = (long long)H_ * N_ * HD_, ui_sh = (long long)N_ * HD_;

    // 3) Attention A: K = KimgA (planar), Q = MSg, V = qkv v-slices (f32),
    //    +resid; outputs u1,u2 as V-images via direct register-scatter
    mattn_kernel<2, true, true, false, false, 1><<<dim3(512), dim3(512), 0, stream>>>(
        MSg, nullptr, KimgA, nullptr,
        qkv1 + 2 * INNER_, nullptr, qkv2 + 2 * INNER_, nullptr,
        (float*)u1img, nullptr, (float*)u2img, nullptr,
        msg_sb, msg_sh, msg_sr,
        kA_sb, kA_sh, 128, 64,
        qkv_sb, qkv_sh, qkv_sr,
        ui_sb, ui_sh, HD_);

    // 4) Attention B merged pair: K = qkv k-slice planar image, V = u images
    //    (one linear gll16 per tile); outputs t1m/t2m as GEMM A-images
    mattn_kernel<1, false, false, true, true, 2><<<dim3(1024), dim3(512), 0, stream>>>(
        qkv1, qkv2,
        (const unsigned short*)qkv1 + 1024, (const unsigned short*)qkv2 + 1024,
        (const float*)u1img, (const float*)u2img, nullptr, nullptr,
        (float*)t1img, (float*)t2img, nullptr, nullptr,
        qkv_sb, qkv_sh, qkv_sr,
        kB_sb, 64, QKVC * 2, 512,
        ui_sb, ui_sh, HD_,
        0, 0, 0);

    // 5) Output projections, MERGED pair (z=2), XCD-swizzled, gll staging
    float* out1 = (float*)d_out;
    float* out2 = out1 + (size_t)M_ * DIM_;
    gemm_gll<true, false, 2><<<dim3(DIM_ / 128, M_ / 128, 2), blk, 0, stream>>>(
        t1img, t2img, wo1t, wo2t, bout1, bout2, out1, out2, M_, DIM_);
}